// Round 1
// baseline (428.546 us; speedup 1.0000x reference)
//
#include <hip/hip_runtime.h>

// ---------------------------------------------------------------------------
// GraphSAGE 3-layer forward, MI355X.
//   CSR build: coarse 256-bucket histogram -> tiny scan -> part_scatter
//     (bucket-grouped int2 edges, dense writes) -> bucket_build (per-bucket
//     LDS count/scan/scatter -> offs + ssrc). No node-level global atomics.
//   Per layer: bf16 MFMA GEMM [y|z] = A @ [Wl;Wr].T (fp32 accum), 64x128
//     tiles (A staged twice per layer, not 4x); y bf16; z bf16 (LN layers)
//     or fp32 (final); layer-0 A converted fp32->bf16 during staging.
//   Aggregation: per-quad direct index loads; TWO edges per quad per iter
//     (2 gathers + 2 index prefetches in flight) to cover gather latency;
//     gather-mean + z + ReLU + LayerNorm -> h (bf16).
// R7->R8: agg kernels 2-edge-deep software pipeline (2x MLP); epilogue
//     z/gamma/beta loads hoisted ahead of the shuffle reductions.
// ---------------------------------------------------------------------------

typedef __bf16 bf16x8 __attribute__((ext_vector_type(8)));
typedef __bf16 bf16x4 __attribute__((ext_vector_type(4)));
typedef float  f32x4  __attribute__((ext_vector_type(4)));

#define PB_SHIFT 9                      // 512 nodes per coarse bucket
#define PB_NB    256                    // covers N <= 131072
#define PB_EPT   8
#define PB_BLOCK 256
#define PB_CHUNK (PB_BLOCK * PB_EPT)    // 2048 edges per block

__global__ __launch_bounds__(PB_BLOCK) void coarse_hist(
    const int* __restrict__ dst, int* __restrict__ bhist, int E) {
    __shared__ int h[PB_NB];
    const int t = threadIdx.x;
    h[t] = 0;
    __syncthreads();
    const int e0 = blockIdx.x * PB_CHUNK + t;
#pragma unroll
    for (int i = 0; i < PB_EPT; ++i) {
        int e = e0 + i * PB_BLOCK;
        if (e < E) atomicAdd(&h[dst[e] >> PB_SHIFT], 1);
    }
    __syncthreads();
    if (h[t]) atomicAdd(&bhist[t], h[t]);
}

__global__ __launch_bounds__(PB_NB) void coarse_scan(
    const int* __restrict__ bhist, int* __restrict__ bbase, int* __restrict__ bcur) {
    __shared__ int sm[PB_NB];
    const int t = threadIdx.x;
    int v = bhist[t];
    sm[t] = v;
    __syncthreads();
    for (int off = 1; off < PB_NB; off <<= 1) {
        int add = (t >= off) ? sm[t - off] : 0;
        __syncthreads();
        sm[t] += add;
        __syncthreads();
    }
    int excl = sm[t] - v;
    bbase[t] = excl;
    bcur[t] = excl;
}

__global__ __launch_bounds__(PB_BLOCK) void part_scatter(
    const int* __restrict__ src, const int* __restrict__ dst,
    int* __restrict__ bcursor, int2* __restrict__ part, int E) {
    __shared__ int hist[PB_NB];
    __shared__ int base[PB_NB];
    const int t = threadIdx.x;
    hist[t] = 0;
    __syncthreads();
    const int e0 = blockIdx.x * PB_CHUNK + t;
    int my_s[PB_EPT], my_d[PB_EPT], my_r[PB_EPT];
#pragma unroll
    for (int i = 0; i < PB_EPT; ++i) {
        int e = e0 + i * PB_BLOCK;
        if (e < E) {
            my_s[i] = src[e];
            my_d[i] = dst[e];
            my_r[i] = atomicAdd(&hist[my_d[i] >> PB_SHIFT], 1);
        }
    }
    __syncthreads();
    {
        int c = hist[t];
        base[t] = c ? atomicAdd(&bcursor[t], c) : 0;
    }
    __syncthreads();
#pragma unroll
    for (int i = 0; i < PB_EPT; ++i) {
        int e = e0 + i * PB_BLOCK;
        if (e < E) {
            int b = my_d[i] >> PB_SHIFT;
            part[base[b] + my_r[i]] = make_int2(my_s[i], my_d[i]);
        }
    }
}

__global__ __launch_bounds__(256) void bucket_build(
    const int2* __restrict__ part, const int* __restrict__ bbase,
    int* __restrict__ offs, int* __restrict__ ssrc, int N, int E) {
    __shared__ int h[512];
    __shared__ int s[512];
    __shared__ int cur[512];
    const int b = blockIdx.x;
    const int t = threadIdx.x;
    const int beg = bbase[b];
    const int end = (b == PB_NB - 1) ? E : bbase[b + 1];

    h[t] = 0; h[t + 256] = 0;
    __syncthreads();
    for (int e = beg + t; e < end; e += 256)
        atomicAdd(&h[part[e].y & 511], 1);
    __syncthreads();
    s[t] = h[t]; s[t + 256] = h[t + 256];
    __syncthreads();
    for (int off = 1; off < 512; off <<= 1) {
        int a0 = (t >= off) ? s[t - off] : 0;
        int i1 = t + 256;
        int a1 = (i1 >= off) ? s[i1 - off] : 0;
        __syncthreads();
        s[t] += a0; s[i1] += a1;
        __syncthreads();
    }
#pragma unroll
    for (int k = 0; k < 2; ++k) {
        int i = t + k * 256;
        int excl = s[i] - h[i];
        cur[i] = excl;
        int node = (b << PB_SHIFT) + i;
        if (node < N) offs[node] = beg + excl;
    }
    if (b == 0 && t == 0) offs[N] = E;
    __syncthreads();
    for (int e = beg + t; e < end; e += 256) {
        int2 sd = part[e];
        int p = atomicAdd(&cur[sd.y & 511], 1);
        ssrc[beg + p] = sd.x;
    }
}

// ---------------------------------------------------------------------------
// MFMA GEMM: out cols = full DOUT of Wl (by=0 -> ybuf bf16) or Wr (by=1 ->
// zbuf + bias). 64 rows x DOUT cols per block, 4 waves each 32 x DOUT/2.
// K=128 LDS-resident (stride 136 bf16 -> 2-way aliasing, free).
// ---------------------------------------------------------------------------
template <int DOUT, typename AT, typename ZT>
__global__ __launch_bounds__(256) void gemm_mfma(
    const AT* __restrict__ A,
    const float* __restrict__ Wl,
    const float* __restrict__ Wr,
    const float* __restrict__ bias,
    __bf16* __restrict__ ybuf,
    ZT*     __restrict__ zbuf,
    int M) {
    __shared__ __bf16 Asm[64 * 136];
    __shared__ __bf16 Bsm[DOUT * 136];

    const int t = threadIdx.x;
    const int rowBase = blockIdx.x * 64;
    const bool isZ = blockIdx.y != 0;
    const float* W = isZ ? Wr : Wl;

    if constexpr (sizeof(AT) == 4) {
#pragma unroll
        for (int i = 0; i < 8; ++i) {
            int idx = t + 256 * i;
            int r = idx >> 5;
            int c4 = idx & 31;
            int grow = rowBase + r;
            if (grow >= M) grow = M - 1;
            float4 v = *(const float4*)((const float*)A + (size_t)grow * 128 + c4 * 4);
            bf16x4 o;
            o[0] = (__bf16)v.x; o[1] = (__bf16)v.y; o[2] = (__bf16)v.z; o[3] = (__bf16)v.w;
            *(bf16x4*)(Asm + r * 136 + c4 * 4) = o;
        }
    } else {
#pragma unroll
        for (int i = 0; i < 4; ++i) {
            int idx = t + 256 * i;
            int r = idx >> 4;
            int c8 = idx & 15;
            int grow = rowBase + r;
            if (grow >= M) grow = M - 1;
            bf16x8 v = *(const bf16x8*)((const __bf16*)A + (size_t)grow * 128 + c8 * 8);
            *(bf16x8*)(Asm + r * 136 + c8 * 8) = v;
        }
    }
    constexpr int BCH = DOUT * 32 / 256;   // float4 chunks per thread
#pragma unroll
    for (int i = 0; i < BCH; ++i) {
        int idx = t + 256 * i;
        int r = idx >> 5;
        int c4 = idx & 31;
        float4 v = *(const float4*)(W + (size_t)r * 128 + c4 * 4);
        bf16x4 o;
        o[0] = (__bf16)v.x; o[1] = (__bf16)v.y; o[2] = (__bf16)v.z; o[3] = (__bf16)v.w;
        *(bf16x4*)(Bsm + r * 136 + c4 * 4) = o;
    }
    __syncthreads();

    const int lane = t & 63;
    const int wid = t >> 6;
    const int mb = (wid >> 1) * 32;              // row half
    const int nbase = (wid & 1) * (DOUT / 2);    // col half
    constexpr int NJ = DOUT / 32;                // 16-col tiles per wave
    const int ln = lane & 15;
    const int qk = lane >> 4;

    f32x4 acc[2][NJ] = {};
#pragma unroll
    for (int ks = 0; ks < 4; ++ks) {
        const int k0 = ks * 32 + qk * 8;
        bf16x8 a0 = *(const bf16x8*)(Asm + (mb + ln) * 136 + k0);
        bf16x8 a1 = *(const bf16x8*)(Asm + (mb + 16 + ln) * 136 + k0);
        bf16x8 b[NJ];
#pragma unroll
        for (int j = 0; j < NJ; ++j)
            b[j] = *(const bf16x8*)(Bsm + (nbase + j * 16 + ln) * 136 + k0);
#pragma unroll
        for (int j = 0; j < NJ; ++j) {
            acc[0][j] = __builtin_amdgcn_mfma_f32_16x16x32_bf16(a0, b[j], acc[0][j], 0, 0, 0);
            acc[1][j] = __builtin_amdgcn_mfma_f32_16x16x32_bf16(a1, b[j], acc[1][j], 0, 0, 0);
        }
    }

    float bcol[NJ];
    if (isZ) {
#pragma unroll
        for (int j = 0; j < NJ; ++j) bcol[j] = bias[nbase + j * 16 + ln];
    }
    // C/D: col = lane&15, row = (lane>>4)*4 + reg  [m89-verified]
#pragma unroll
    for (int i = 0; i < 2; ++i) {
#pragma unroll
        for (int r = 0; r < 4; ++r) {
            int grow = rowBase + mb + i * 16 + qk * 4 + r;
            if (grow >= M) continue;
#pragma unroll
            for (int j = 0; j < NJ; ++j) {
                int col = nbase + j * 16 + ln;
                float v = acc[i][j][r];
                if (isZ) zbuf[(size_t)grow * DOUT + col] = (ZT)(v + bcol[j]);
                else     ybuf[(size_t)grow * DOUT + col] = (__bf16)v;
            }
        }
    }
}

// ---------------------------------------------------------------------------
// Aggregation 128f: one wave per node; 16-lane quads each handle TWO edges
// per iter (stride 8), loading both payload gathers back-to-back before the
// two next-iter index prefetches -> 4 loads in flight per quad.
// mean(y bf16) + z(bf16) -> ReLU -> LN -> h (bf16).
// ---------------------------------------------------------------------------
__global__ __launch_bounds__(256) void agg_ln128(
    const int* __restrict__ offs, const int* __restrict__ ssrc,
    const __bf16* __restrict__ ybuf,   // [N][128]
    const __bf16* __restrict__ zbuf,   // [N][128]
    const float* __restrict__ gamma, const float* __restrict__ beta,
    __bf16* __restrict__ hout, int nNodes) {
    const int lane = threadIdx.x & 63;
    const int qh = lane >> 4;
    const int li = lane & 15;
    const int node = blockIdx.x * 4 + (threadIdx.x >> 6);
    if (node >= nNodes) return;
    const int beg = offs[node], end = offs[node + 1];
    const int deg = end - beg;

    float acc[8] = {};
    const int iters = (deg + 7) >> 3;            // 2 edges / quad / iter
    int eA = beg + qh;
    int eB = eA + 4;
    int idxA = 0, idxB = 0;
    if (iters > 0) {
        idxA = ssrc[(eA < end) ? eA : beg];
        idxB = ssrc[(eB < end) ? eB : beg];
    }
    for (int u = 0; u < iters; ++u) {
        const bool va = eA < end;
        const bool vb = eB < end;
        uint4 uva, uvb;
        if (va) uva = *(const uint4*)(ybuf + (size_t)idxA * 128 + li * 8);
        if (vb) uvb = *(const uint4*)(ybuf + (size_t)idxB * 128 + li * 8);
        int eA2 = eA + 8, eB2 = eB + 8;
        int idxA2 = ssrc[(eA2 < end) ? eA2 : beg];   // prefetch next pair
        int idxB2 = ssrc[(eB2 < end) ? eB2 : beg];
        if (va) {
            acc[0] += __uint_as_float(uva.x << 16);
            acc[1] += __uint_as_float(uva.x & 0xffff0000u);
            acc[2] += __uint_as_float(uva.y << 16);
            acc[3] += __uint_as_float(uva.y & 0xffff0000u);
            acc[4] += __uint_as_float(uva.z << 16);
            acc[5] += __uint_as_float(uva.z & 0xffff0000u);
            acc[6] += __uint_as_float(uva.w << 16);
            acc[7] += __uint_as_float(uva.w & 0xffff0000u);
        }
        if (vb) {
            acc[0] += __uint_as_float(uvb.x << 16);
            acc[1] += __uint_as_float(uvb.x & 0xffff0000u);
            acc[2] += __uint_as_float(uvb.y << 16);
            acc[3] += __uint_as_float(uvb.y & 0xffff0000u);
            acc[4] += __uint_as_float(uvb.z << 16);
            acc[5] += __uint_as_float(uvb.z & 0xffff0000u);
            acc[6] += __uint_as_float(uvb.w << 16);
            acc[7] += __uint_as_float(uvb.w & 0xffff0000u);
        }
        eA = eA2; eB = eB2; idxA = idxA2; idxB = idxB2;
    }

    // epilogue loads issued before the shuffle chains to overlap latency
    bf16x8 zv = *(const bf16x8*)(zbuf + (size_t)node * 128 + li * 8);
    const float4* g4 = (const float4*)(gamma + li * 8);
    const float4* b4 = (const float4*)(beta + li * 8);
    float4 g0 = g4[0], g1 = g4[1], bb0 = b4[0], bb1 = b4[1];

#pragma unroll
    for (int m = 0; m < 8; ++m) {
        acc[m] += __shfl_xor(acc[m], 16, 64);
        acc[m] += __shfl_xor(acc[m], 32, 64);
    }
    float inv = 1.f / (float)((deg > 1) ? deg : 1);
    float v[8];
#pragma unroll
    for (int m = 0; m < 8; ++m) v[m] = fmaxf(acc[m] * inv + (float)zv[m], 0.f);

    float s = 0.f;
#pragma unroll
    for (int m = 0; m < 8; ++m) s += v[m];
#pragma unroll
    for (int off = 8; off >= 1; off >>= 1) s += __shfl_xor(s, off, 64);
    float mu = s * (1.f / 128.f);
    float d[8], q = 0.f;
#pragma unroll
    for (int m = 0; m < 8; ++m) { d[m] = v[m] - mu; q += d[m] * d[m]; }
#pragma unroll
    for (int off = 8; off >= 1; off >>= 1) q += __shfl_xor(q, off, 64);
    float rstd = rsqrtf(q * (1.f / 128.f) + 1e-5f);

    if (qh == 0) {
        bf16x8 o;
        o[0] = (__bf16)(d[0] * rstd * g0.x + bb0.x);
        o[1] = (__bf16)(d[1] * rstd * g0.y + bb0.y);
        o[2] = (__bf16)(d[2] * rstd * g0.z + bb0.z);
        o[3] = (__bf16)(d[3] * rstd * g0.w + bb0.w);
        o[4] = (__bf16)(d[4] * rstd * g1.x + bb1.x);
        o[5] = (__bf16)(d[5] * rstd * g1.y + bb1.y);
        o[6] = (__bf16)(d[6] * rstd * g1.z + bb1.z);
        o[7] = (__bf16)(d[7] * rstd * g1.w + bb1.w);
        *(bf16x8*)(hout + (size_t)node * 128 + li * 8) = o;
    }
}

// Aggregation 64f (final): 8-lane groups each handle TWO edges per iter
// (stride 16; 2 gathers + 2 index prefetches in flight);
// mean(y bf16) + z(fp32) -> out fp32.
__global__ __launch_bounds__(256) void agg_out64(
    const int* __restrict__ offs, const int* __restrict__ ssrc,
    const __bf16* __restrict__ ybuf,   // [N][64]
    const float* __restrict__ zbuf,    // [N][64]
    float* __restrict__ out, int nNodes) {
    const int lane = threadIdx.x & 63;
    const int eh = lane >> 3;
    const int li = lane & 7;
    const int node = blockIdx.x * 4 + (threadIdx.x >> 6);
    if (node >= nNodes) return;
    const int beg = offs[node], end = offs[node + 1];
    const int deg = end - beg;

    float acc[8] = {};
    const int iters = (deg + 15) >> 4;           // 2 edges / group / iter
    int eA = beg + eh;
    int eB = eA + 8;
    int idxA = 0, idxB = 0;
    if (iters > 0) {
        idxA = ssrc[(eA < end) ? eA : beg];
        idxB = ssrc[(eB < end) ? eB : beg];
    }
    for (int u = 0; u < iters; ++u) {
        const bool va = eA < end;
        const bool vb = eB < end;
        uint4 uva, uvb;
        if (va) uva = *(const uint4*)(ybuf + (size_t)idxA * 64 + li * 8);
        if (vb) uvb = *(const uint4*)(ybuf + (size_t)idxB * 64 + li * 8);
        int eA2 = eA + 16, eB2 = eB + 16;
        int idxA2 = ssrc[(eA2 < end) ? eA2 : beg];
        int idxB2 = ssrc[(eB2 < end) ? eB2 : beg];
        if (va) {
            acc[0] += __uint_as_float(uva.x << 16);
            acc[1] += __uint_as_float(uva.x & 0xffff0000u);
            acc[2] += __uint_as_float(uva.y << 16);
            acc[3] += __uint_as_float(uva.y & 0xffff0000u);
            acc[4] += __uint_as_float(uva.z << 16);
            acc[5] += __uint_as_float(uva.z & 0xffff0000u);
            acc[6] += __uint_as_float(uva.w << 16);
            acc[7] += __uint_as_float(uva.w & 0xffff0000u);
        }
        if (vb) {
            acc[0] += __uint_as_float(uvb.x << 16);
            acc[1] += __uint_as_float(uvb.x & 0xffff0000u);
            acc[2] += __uint_as_float(uvb.y << 16);
            acc[3] += __uint_as_float(uvb.y & 0xffff0000u);
            acc[4] += __uint_as_float(uvb.z << 16);
            acc[5] += __uint_as_float(uvb.z & 0xffff0000u);
            acc[6] += __uint_as_float(uvb.w << 16);
            acc[7] += __uint_as_float(uvb.w & 0xffff0000u);
        }
        eA = eA2; eB = eB2; idxA = idxA2; idxB = idxB2;
    }

    const float4* z4 = (const float4*)(zbuf + (size_t)node * 64 + li * 8);
    float4 z0 = z4[0], z1 = z4[1];

#pragma unroll
    for (int m = 0; m < 8; ++m) {
        acc[m] += __shfl_xor(acc[m], 8, 64);
        acc[m] += __shfl_xor(acc[m], 16, 64);
        acc[m] += __shfl_xor(acc[m], 32, 64);
    }
    if (eh == 0) {
        float inv = 1.f / (float)((deg > 1) ? deg : 1);
        float4 o0, o1;
        o0.x = acc[0] * inv + z0.x;
        o0.y = acc[1] * inv + z0.y;
        o0.z = acc[2] * inv + z0.z;
        o0.w = acc[3] * inv + z0.w;
        o1.x = acc[4] * inv + z1.x;
        o1.y = acc[5] * inv + z1.y;
        o1.z = acc[6] * inv + z1.z;
        o1.w = acc[7] * inv + z1.w;
        float4* op = (float4*)(out + (size_t)node * 64 + li * 8);
        op[0] = o0;
        op[1] = o1;
    }
}

// ---------------------------------------------------------------------------
extern "C" void kernel_launch(void* const* d_in, const int* in_sizes, int n_in,
                              void* d_out, int out_size, void* d_ws, size_t ws_size,
                              hipStream_t stream) {
    const float* x   = (const float*)d_in[0];
    const int*   ei  = (const int*)d_in[1];
    const float* Wl0 = (const float*)d_in[2];
    const float* Wr0 = (const float*)d_in[3];
    const float* b0  = (const float*)d_in[4];
    const float* Wl1 = (const float*)d_in[5];
    const float* Wr1 = (const float*)d_in[6];
    const float* b1  = (const float*)d_in[7];
    const float* Wl2 = (const float*)d_in[8];
    const float* Wr2 = (const float*)d_in[9];
    const float* b2  = (const float*)d_in[10];
    const float* g0  = (const float*)d_in[11];
    const float* be0 = (const float*)d_in[12];
    const float* g1  = (const float*)d_in[13];
    const float* be1 = (const float*)d_in[14];

    const int N = in_sizes[0] / 128;
    const int E = in_sizes[1] / 2;
    const int* src = ei;
    const int* dst = ei + E;
    float* out = (float*)d_out;

    char* p = (char*)d_ws;
    auto carve = [&](size_t bytes) {
        void* q = (void*)p;
        p += (bytes + 255) & ~(size_t)255;
        return q;
    };
    int*     offs  = (int*)carve(sizeof(int) * (size_t)(N + 1));
    int*     bhist = (int*)carve(sizeof(int) * (size_t)PB_NB);
    int*     bbase = (int*)carve(sizeof(int) * (size_t)PB_NB);
    int*     bcur  = (int*)carve(sizeof(int) * (size_t)PB_NB);
    int*     ssrc  = (int*)carve(sizeof(int) * (size_t)E);
    int2*    part  = (int2*)carve(sizeof(int2) * (size_t)E);
    __bf16*  h     = (__bf16*)carve(sizeof(__bf16) * (size_t)N * 128);
    __bf16*  ybuf  = (__bf16*)carve(sizeof(__bf16) * (size_t)N * 128);
    void*    zraw  = carve(sizeof(__bf16) * (size_t)N * 128);  // aliased
    __bf16*  zb    = (__bf16*)zraw;   // LN layers: [N][128] bf16
    float*   zf    = (float*)zraw;    // final layer: [N][64] fp32

    // --- CSR build ---
    hipMemsetAsync(bhist, 0, sizeof(int) * PB_NB, stream);
    const int gridE = (E + PB_CHUNK - 1) / PB_CHUNK;
    coarse_hist<<<gridE, PB_BLOCK, 0, stream>>>(dst, bhist, E);
    coarse_scan<<<1, PB_NB, 0, stream>>>(bhist, bbase, bcur);
    part_scatter<<<gridE, PB_BLOCK, 0, stream>>>(src, dst, bcur, part, E);
    bucket_build<<<PB_NB, 256, 0, stream>>>(part, bbase, offs, ssrc, N, E);

    const int gridM = (N + 63) / 64;
    const int gridNode = (N + 3) / 4;

    // --- Layer 0 (A fp32, converted in staging) ---
    gemm_mfma<128, float, __bf16><<<dim3(gridM, 2), 256, 0, stream>>>(x, Wl0, Wr0, b0, ybuf, zb, N);
    agg_ln128<<<gridNode, 256, 0, stream>>>(offs, ssrc, ybuf, zb, g0, be0, h, N);
    // --- Layer 1 ---
    gemm_mfma<128, __bf16, __bf16><<<dim3(gridM, 2), 256, 0, stream>>>(h, Wl1, Wr1, b1, ybuf, zb, N);
    agg_ln128<<<gridNode, 256, 0, stream>>>(offs, ssrc, ybuf, zb, g1, be1, h, N);
    // --- Layer 2 (64 feats, z fp32, no LN/ReLU) ---
    gemm_mfma<64, __bf16, float><<<dim3(gridM, 2), 256, 0, stream>>>(h, Wl2, Wr2, b2, ybuf, zf, N);
    agg_out64<<<gridNode, 256, 0, stream>>>(offs, ssrc, ybuf, zf, out, N);
}

// Round 4
// 426.259 us; speedup vs baseline: 1.0054x; 1.0054x over previous
//
#include <hip/hip_runtime.h>

// ---------------------------------------------------------------------------
// GraphSAGE 3-layer forward, MI355X.
//   CSR build: coarse 256-bucket histogram -> tiny scan -> part_scatter
//     (bucket-grouped int2 edges, dense writes) -> bucket_build (per-bucket
//     LDS count/scan/scatter -> offs + ssrc). No node-level global atomics.
//   Per layer: bf16 MFMA GEMM [y|z] = A @ [Wl;Wr].T (fp32 accum), 64x128
//     tiles; y quantized to per-row symmetric INT8 (excess-128) + fp32 row
//     scale -- halves the random-gather bytes (binding term: per-XCD L2
//     replication of ybuf) with absmax err <= rowmax/254 (fp8 e4m3 failed at
//     0.125 = half-ULP @|y|~4); z bf16 (LN layers) / fp32 (final) full prec.
//   Aggregation: per-quad direct index loads, 2 edges in flight; int8 rows
//     decoded v_cvt_f32_ubyte + FMA by row scale (scale array 400KB,
//     L2-resident broadcast); -128 bias folded via sum-of-scales.
// R10->R11: fp8 -> per-row int8 (absmax 0.125 -> ~0.05 predicted).
// ---------------------------------------------------------------------------

typedef __bf16 bf16x8 __attribute__((ext_vector_type(8)));
typedef __bf16 bf16x4 __attribute__((ext_vector_type(4)));
typedef float  f32x4  __attribute__((ext_vector_type(4)));

// accumulate 8 excess-128 u8 (two dwords) scaled by s into acc[0..7]
__device__ __forceinline__ void u8_acc8(uint2 w, float s, float* acc) {
    acc[0] += s * (float)( w.x        & 0xffu);   // v_cvt_f32_ubyte0
    acc[1] += s * (float)((w.x >>  8) & 0xffu);   // v_cvt_f32_ubyte1
    acc[2] += s * (float)((w.x >> 16) & 0xffu);   // v_cvt_f32_ubyte2
    acc[3] += s * (float)( w.x >> 24        );    // v_cvt_f32_ubyte3
    acc[4] += s * (float)( w.y        & 0xffu);
    acc[5] += s * (float)((w.y >>  8) & 0xffu);
    acc[6] += s * (float)((w.y >> 16) & 0xffu);
    acc[7] += s * (float)( w.y >> 24        );
}

#define PB_SHIFT 9                      // 512 nodes per coarse bucket
#define PB_NB    256                    // covers N <= 131072
#define PB_EPT   8
#define PB_BLOCK 256
#define PB_CHUNK (PB_BLOCK * PB_EPT)    // 2048 edges per block

__global__ __launch_bounds__(PB_BLOCK) void coarse_hist(
    const int* __restrict__ dst, int* __restrict__ bhist, int E) {
    __shared__ int h[PB_NB];
    const int t = threadIdx.x;
    h[t] = 0;
    __syncthreads();
    const int e0 = blockIdx.x * PB_CHUNK + t;
#pragma unroll
    for (int i = 0; i < PB_EPT; ++i) {
        int e = e0 + i * PB_BLOCK;
        if (e < E) atomicAdd(&h[dst[e] >> PB_SHIFT], 1);
    }
    __syncthreads();
    if (h[t]) atomicAdd(&bhist[t], h[t]);
}

__global__ __launch_bounds__(PB_NB) void coarse_scan(
    const int* __restrict__ bhist, int* __restrict__ bbase, int* __restrict__ bcur) {
    __shared__ int sm[PB_NB];
    const int t = threadIdx.x;
    int v = bhist[t];
    sm[t] = v;
    __syncthreads();
    for (int off = 1; off < PB_NB; off <<= 1) {
        int add = (t >= off) ? sm[t - off] : 0;
        __syncthreads();
        sm[t] += add;
        __syncthreads();
    }
    int excl = sm[t] - v;
    bbase[t] = excl;
    bcur[t] = excl;
}

__global__ __launch_bounds__(PB_BLOCK) void part_scatter(
    const int* __restrict__ src, const int* __restrict__ dst,
    int* __restrict__ bcursor, int2* __restrict__ part, int E) {
    __shared__ int hist[PB_NB];
    __shared__ int base[PB_NB];
    const int t = threadIdx.x;
    hist[t] = 0;
    __syncthreads();
    const int e0 = blockIdx.x * PB_CHUNK + t;
    int my_s[PB_EPT], my_d[PB_EPT], my_r[PB_EPT];
#pragma unroll
    for (int i = 0; i < PB_EPT; ++i) {
        int e = e0 + i * PB_BLOCK;
        if (e < E) {
            my_s[i] = src[e];
            my_d[i] = dst[e];
            my_r[i] = atomicAdd(&hist[my_d[i] >> PB_SHIFT], 1);
        }
    }
    __syncthreads();
    {
        int c = hist[t];
        base[t] = c ? atomicAdd(&bcursor[t], c) : 0;
    }
    __syncthreads();
#pragma unroll
    for (int i = 0; i < PB_EPT; ++i) {
        int e = e0 + i * PB_BLOCK;
        if (e < E) {
            int b = my_d[i] >> PB_SHIFT;
            part[base[b] + my_r[i]] = make_int2(my_s[i], my_d[i]);
        }
    }
}

__global__ __launch_bounds__(256) void bucket_build(
    const int2* __restrict__ part, const int* __restrict__ bbase,
    int* __restrict__ offs, int* __restrict__ ssrc, int N, int E) {
    __shared__ int h[512];
    __shared__ int s[512];
    __shared__ int cur[512];
    const int b = blockIdx.x;
    const int t = threadIdx.x;
    const int beg = bbase[b];
    const int end = (b == PB_NB - 1) ? E : bbase[b + 1];

    h[t] = 0; h[t + 256] = 0;
    __syncthreads();
    for (int e = beg + t; e < end; e += 256)
        atomicAdd(&h[part[e].y & 511], 1);
    __syncthreads();
    s[t] = h[t]; s[t + 256] = h[t + 256];
    __syncthreads();
    for (int off = 1; off < 512; off <<= 1) {
        int a0 = (t >= off) ? s[t - off] : 0;
        int i1 = t + 256;
        int a1 = (i1 >= off) ? s[i1 - off] : 0;
        __syncthreads();
        s[t] += a0; s[i1] += a1;
        __syncthreads();
    }
#pragma unroll
    for (int k = 0; k < 2; ++k) {
        int i = t + k * 256;
        int excl = s[i] - h[i];
        cur[i] = excl;
        int node = (b << PB_SHIFT) + i;
        if (node < N) offs[node] = beg + excl;
    }
    if (b == 0 && t == 0) offs[N] = E;
    __syncthreads();
    for (int e = beg + t; e < end; e += 256) {
        int2 sd = part[e];
        int p = atomicAdd(&cur[sd.y & 511], 1);
        ssrc[beg + p] = sd.x;
    }
}

// ---------------------------------------------------------------------------
// MFMA GEMM: out cols = full DOUT of Wl (by=0 -> ybuf int8 + yscale) or Wr
// (by=1 -> zbuf + bias). 64 rows x DOUT cols per block, 4 waves each
// 32 x DOUT/2. K=128 LDS-resident (stride 136 bf16 -> 2-way alias, free).
// y epilogue: 16-lane |max| reduce -> LDS cross-wave rowmax -> s=rowmax/127,
// store u8 = rint(v/s)+128 and yscale[row]=s.
// ---------------------------------------------------------------------------
template <int DOUT, typename AT, typename ZT>
__global__ __launch_bounds__(256) void gemm_mfma(
    const AT* __restrict__ A,
    const float* __restrict__ Wl,
    const float* __restrict__ Wr,
    const float* __restrict__ bias,
    unsigned char* __restrict__ ybuf,   // [M][DOUT] u8 (excess-128)
    float*         __restrict__ yscale, // [M]
    ZT*            __restrict__ zbuf,
    int M) {
    __shared__ __bf16 Asm[64 * 136];
    __shared__ __bf16 Bsm[DOUT * 136];
    __shared__ float  rmx[2][64];

    const int t = threadIdx.x;
    const int rowBase = blockIdx.x * 64;
    const bool isZ = blockIdx.y != 0;
    const float* W = isZ ? Wr : Wl;

    if constexpr (sizeof(AT) == 4) {
#pragma unroll
        for (int i = 0; i < 8; ++i) {
            int idx = t + 256 * i;
            int r = idx >> 5;
            int c4 = idx & 31;
            int grow = rowBase + r;
            if (grow >= M) grow = M - 1;
            float4 v = *(const float4*)((const float*)A + (size_t)grow * 128 + c4 * 4);
            bf16x4 o;
            o[0] = (__bf16)v.x; o[1] = (__bf16)v.y; o[2] = (__bf16)v.z; o[3] = (__bf16)v.w;
            *(bf16x4*)(Asm + r * 136 + c4 * 4) = o;
        }
    } else {
#pragma unroll
        for (int i = 0; i < 4; ++i) {
            int idx = t + 256 * i;
            int r = idx >> 4;
            int c8 = idx & 15;
            int grow = rowBase + r;
            if (grow >= M) grow = M - 1;
            bf16x8 v = *(const bf16x8*)((const __bf16*)A + (size_t)grow * 128 + c8 * 8);
            *(bf16x8*)(Asm + r * 136 + c8 * 8) = v;
        }
    }
    constexpr int BCH = DOUT * 32 / 256;   // float4 chunks per thread
#pragma unroll
    for (int i = 0; i < BCH; ++i) {
        int idx = t + 256 * i;
        int r = idx >> 5;
        int c4 = idx & 31;
        float4 v = *(const float4*)(W + (size_t)r * 128 + c4 * 4);
        bf16x4 o;
        o[0] = (__bf16)v.x; o[1] = (__bf16)v.y; o[2] = (__bf16)v.z; o[3] = (__bf16)v.w;
        *(bf16x4*)(Bsm + r * 136 + c4 * 4) = o;
    }
    __syncthreads();

    const int lane = t & 63;
    const int wid = t >> 6;
    const int mb = (wid >> 1) * 32;              // row half
    const int nbase = (wid & 1) * (DOUT / 2);    // col half
    constexpr int NJ = DOUT / 32;                // 16-col tiles per wave
    const int ln = lane & 15;
    const int qk = lane >> 4;

    f32x4 acc[2][NJ] = {};
#pragma unroll
    for (int ks = 0; ks < 4; ++ks) {
        const int k0 = ks * 32 + qk * 8;
        bf16x8 a0 = *(const bf16x8*)(Asm + (mb + ln) * 136 + k0);
        bf16x8 a1 = *(const bf16x8*)(Asm + (mb + 16 + ln) * 136 + k0);
        bf16x8 b[NJ];
#pragma unroll
        for (int j = 0; j < NJ; ++j)
            b[j] = *(const bf16x8*)(Bsm + (nbase + j * 16 + ln) * 136 + k0);
#pragma unroll
        for (int j = 0; j < NJ; ++j) {
            acc[0][j] = __builtin_amdgcn_mfma_f32_16x16x32_bf16(a0, b[j], acc[0][j], 0, 0, 0);
            acc[1][j] = __builtin_amdgcn_mfma_f32_16x16x32_bf16(a1, b[j], acc[1][j], 0, 0, 0);
        }
    }

    // C/D: col = lane&15, row = (lane>>4)*4 + reg  [m89-verified]
    if (isZ) {
        float bcol[NJ];
#pragma unroll
        for (int j = 0; j < NJ; ++j) bcol[j] = bias[nbase + j * 16 + ln];
#pragma unroll
        for (int i = 0; i < 2; ++i) {
#pragma unroll
            for (int r = 0; r < 4; ++r) {
                int grow = rowBase + mb + i * 16 + qk * 4 + r;
                if (grow >= M) continue;
#pragma unroll
                for (int j = 0; j < NJ; ++j) {
                    int col = nbase + j * 16 + ln;
                    zbuf[(size_t)grow * DOUT + col] = (ZT)(acc[i][j][r] + bcol[j]);
                }
            }
        }
    } else {
        // per-row |max| over this wave's col-half, 16-lane butterfly
#pragma unroll
        for (int i = 0; i < 2; ++i) {
#pragma unroll
            for (int r = 0; r < 4; ++r) {
                float m = 0.f;
#pragma unroll
                for (int j = 0; j < NJ; ++j) m = fmaxf(m, fabsf(acc[i][j][r]));
#pragma unroll
                for (int o = 1; o < 16; o <<= 1) m = fmaxf(m, __shfl_xor(m, o, 64));
                if (ln == 0) rmx[wid & 1][mb + i * 16 + qk * 4 + r] = m;
            }
        }
        __syncthreads();
#pragma unroll
        for (int i = 0; i < 2; ++i) {
#pragma unroll
            for (int r = 0; r < 4; ++r) {
                int rb = mb + i * 16 + qk * 4 + r;
                int grow = rowBase + rb;
                if (grow >= M) continue;
                float rm = fmaxf(fmaxf(rmx[0][rb], rmx[1][rb]), 1e-20f);
                float sc = rm * (1.f / 127.f);
                float rs = 127.f / rm;
                if ((wid & 1) == 0 && ln == 0) yscale[grow] = sc;
#pragma unroll
                for (int j = 0; j < NJ; ++j) {
                    int col = nbase + j * 16 + ln;
                    float q = rintf(acc[i][j][r] * rs) + 128.f;
                    ybuf[(size_t)grow * DOUT + col] = (unsigned char)q;
                }
            }
        }
    }
}

// ---------------------------------------------------------------------------
// Aggregation 128f: one wave per node; 16-lane quads each handle TWO edges
// per iter (stride 8); int8 rows (128B) + broadcast row scale; decode via
// v_cvt_f32_ubyte + fmac; excess-128 bias folded via sum-of-scales.
// mean + z(bf16) -> ReLU -> LN -> h (bf16).
// ---------------------------------------------------------------------------
__global__ __launch_bounds__(256) void agg_ln128(
    const int* __restrict__ offs, const int* __restrict__ ssrc,
    const unsigned char* __restrict__ ybuf,   // [N][128] u8
    const float* __restrict__ yscale,         // [N]
    const __bf16* __restrict__ zbuf,          // [N][128] bf16
    const float* __restrict__ gamma, const float* __restrict__ beta,
    __bf16* __restrict__ hout, int nNodes) {
    const int lane = threadIdx.x & 63;
    const int qh = lane >> 4;
    const int li = lane & 15;
    const int node = blockIdx.x * 4 + (threadIdx.x >> 6);
    if (node >= nNodes) return;
    const int beg = offs[node], end = offs[node + 1];
    const int deg = end - beg;

    float acc[8] = {};
    float sS = 0.f;
    const int iters = (deg + 7) >> 3;            // 2 edges / quad / iter
    int eA = beg + qh;
    int eB = eA + 4;
    int idxA = 0, idxB = 0;
    if (iters > 0) {
        idxA = ssrc[(eA < end) ? eA : beg];
        idxB = ssrc[(eB < end) ? eB : beg];
    }
    for (int u = 0; u < iters; ++u) {
        const bool va = eA < end;
        const bool vb = eB < end;
        uint2 wa, wb;
        float sa = 0.f, sb = 0.f;
        if (va) { wa = *(const uint2*)(ybuf + (((unsigned)idxA) << 7) + li * 8); sa = yscale[idxA]; }
        if (vb) { wb = *(const uint2*)(ybuf + (((unsigned)idxB) << 7) + li * 8); sb = yscale[idxB]; }
        int eA2 = eA + 8, eB2 = eB + 8;
        int idxA2 = ssrc[(eA2 < end) ? eA2 : beg];   // prefetch next pair
        int idxB2 = ssrc[(eB2 < end) ? eB2 : beg];
        if (va) { u8_acc8(wa, sa, acc); sS += sa; }
        if (vb) { u8_acc8(wb, sb, acc); sS += sb; }
        eA = eA2; eB = eB2; idxA = idxA2; idxB = idxB2;
    }

    // epilogue loads issued before the shuffle chains to overlap latency
    bf16x8 zv = *(const bf16x8*)(zbuf + (size_t)node * 128 + li * 8);
    const float4* g4 = (const float4*)(gamma + li * 8);
    const float4* b4 = (const float4*)(beta + li * 8);
    float4 g0 = g4[0], g1 = g4[1], bb0 = b4[0], bb1 = b4[1];

    sS += __shfl_xor(sS, 16, 64);
    sS += __shfl_xor(sS, 32, 64);
#pragma unroll
    for (int m = 0; m < 8; ++m) {
        acc[m] += __shfl_xor(acc[m], 16, 64);
        acc[m] += __shfl_xor(acc[m], 32, 64);
    }
    float inv = 1.f / (float)((deg > 1) ? deg : 1);
    float v[8];
#pragma unroll
    for (int m = 0; m < 8; ++m)
        v[m] = fmaxf((acc[m] - 128.f * sS) * inv + (float)zv[m], 0.f);

    float s = 0.f;
#pragma unroll
    for (int m = 0; m < 8; ++m) s += v[m];
#pragma unroll
    for (int off = 8; off >= 1; off >>= 1) s += __shfl_xor(s, off, 64);
    float mu = s * (1.f / 128.f);
    float d[8], q = 0.f;
#pragma unroll
    for (int m = 0; m < 8; ++m) { d[m] = v[m] - mu; q += d[m] * d[m]; }
#pragma unroll
    for (int off = 8; off >= 1; off >>= 1) q += __shfl_xor(q, off, 64);
    float rstd = rsqrtf(q * (1.f / 128.f) + 1e-5f);

    if (qh == 0) {
        bf16x8 o;
        o[0] = (__bf16)(d[0] * rstd * g0.x + bb0.x);
        o[1] = (__bf16)(d[1] * rstd * g0.y + bb0.y);
        o[2] = (__bf16)(d[2] * rstd * g0.z + bb0.z);
        o[3] = (__bf16)(d[3] * rstd * g0.w + bb0.w);
        o[4] = (__bf16)(d[4] * rstd * g1.x + bb1.x);
        o[5] = (__bf16)(d[5] * rstd * g1.y + bb1.y);
        o[6] = (__bf16)(d[6] * rstd * g1.z + bb1.z);
        o[7] = (__bf16)(d[7] * rstd * g1.w + bb1.w);
        *(bf16x8*)(hout + (size_t)node * 128 + li * 8) = o;
    }
}

// Aggregation 64f (final): 8-lane groups each handle TWO edges per iter
// (stride 16); int8 rows (64B) + scale; mean + z(fp32) -> out fp32.
__global__ __launch_bounds__(256) void agg_out64(
    const int* __restrict__ offs, const int* __restrict__ ssrc,
    const unsigned char* __restrict__ ybuf,   // [N][64] u8
    const float* __restrict__ yscale,         // [N]
    const float* __restrict__ zbuf,           // [N][64]
    float* __restrict__ out, int nNodes) {
    const int lane = threadIdx.x & 63;
    const int eh = lane >> 3;
    const int li = lane & 7;
    const int node = blockIdx.x * 4 + (threadIdx.x >> 6);
    if (node >= nNodes) return;
    const int beg = offs[node], end = offs[node + 1];
    const int deg = end - beg;

    float acc[8] = {};
    float sS = 0.f;
    const int iters = (deg + 15) >> 4;           // 2 edges / group / iter
    int eA = beg + eh;
    int eB = eA + 8;
    int idxA = 0, idxB = 0;
    if (iters > 0) {
        idxA = ssrc[(eA < end) ? eA : beg];
        idxB = ssrc[(eB < end) ? eB : beg];
    }
    for (int u = 0; u < iters; ++u) {
        const bool va = eA < end;
        const bool vb = eB < end;
        uint2 wa, wb;
        float sa = 0.f, sb = 0.f;
        if (va) { wa = *(const uint2*)(ybuf + (((unsigned)idxA) << 6) + li * 8); sa = yscale[idxA]; }
        if (vb) { wb = *(const uint2*)(ybuf + (((unsigned)idxB) << 6) + li * 8); sb = yscale[idxB]; }
        int eA2 = eA + 16, eB2 = eB + 16;
        int idxA2 = ssrc[(eA2 < end) ? eA2 : beg];
        int idxB2 = ssrc[(eB2 < end) ? eB2 : beg];
        if (va) { u8_acc8(wa, sa, acc); sS += sa; }
        if (vb) { u8_acc8(wb, sb, acc); sS += sb; }
        eA = eA2; eB = eB2; idxA = idxA2; idxB = idxB2;
    }

    const float4* z4 = (const float4*)(zbuf + (size_t)node * 64 + li * 8);
    float4 z0 = z4[0], z1 = z4[1];

    sS += __shfl_xor(sS, 8, 64);
    sS += __shfl_xor(sS, 16, 64);
    sS += __shfl_xor(sS, 32, 64);
#pragma unroll
    for (int m = 0; m < 8; ++m) {
        acc[m] += __shfl_xor(acc[m], 8, 64);
        acc[m] += __shfl_xor(acc[m], 16, 64);
        acc[m] += __shfl_xor(acc[m], 32, 64);
    }
    if (eh == 0) {
        float inv = 1.f / (float)((deg > 1) ? deg : 1);
        float4 o0, o1;
        o0.x = (acc[0] - 128.f * sS) * inv + z0.x;
        o0.y = (acc[1] - 128.f * sS) * inv + z0.y;
        o0.z = (acc[2] - 128.f * sS) * inv + z0.z;
        o0.w = (acc[3] - 128.f * sS) * inv + z0.w;
        o1.x = (acc[4] - 128.f * sS) * inv + z1.x;
        o1.y = (acc[5] - 128.f * sS) * inv + z1.y;
        o1.z = (acc[6] - 128.f * sS) * inv + z1.z;
        o1.w = (acc[7] - 128.f * sS) * inv + z1.w;
        float4* op = (float4*)(out + (size_t)node * 64 + li * 8);
        op[0] = o0;
        op[1] = o1;
    }
}

// ---------------------------------------------------------------------------
extern "C" void kernel_launch(void* const* d_in, const int* in_sizes, int n_in,
                              void* d_out, int out_size, void* d_ws, size_t ws_size,
                              hipStream_t stream) {
    const float* x   = (const float*)d_in[0];
    const int*   ei  = (const int*)d_in[1];
    const float* Wl0 = (const float*)d_in[2];
    const float* Wr0 = (const float*)d_in[3];
    const float* b0  = (const float*)d_in[4];
    const float* Wl1 = (const float*)d_in[5];
    const float* Wr1 = (const float*)d_in[6];
    const float* b1  = (const float*)d_in[7];
    const float* Wl2 = (const float*)d_in[8];
    const float* Wr2 = (const float*)d_in[9];
    const float* b2  = (const float*)d_in[10];
    const float* g0  = (const float*)d_in[11];
    const float* be0 = (const float*)d_in[12];
    const float* g1  = (const float*)d_in[13];
    const float* be1 = (const float*)d_in[14];

    const int N = in_sizes[0] / 128;
    const int E = in_sizes[1] / 2;
    const int* src = ei;
    const int* dst = ei + E;
    float* out = (float*)d_out;

    char* p = (char*)d_ws;
    auto carve = [&](size_t bytes) {
        void* q = (void*)p;
        p += (bytes + 255) & ~(size_t)255;
        return q;
    };
    int*     offs   = (int*)carve(sizeof(int) * (size_t)(N + 1));
    int*     bhist  = (int*)carve(sizeof(int) * (size_t)PB_NB);
    int*     bbase  = (int*)carve(sizeof(int) * (size_t)PB_NB);
    int*     bcur   = (int*)carve(sizeof(int) * (size_t)PB_NB);
    int*     ssrc   = (int*)carve(sizeof(int) * (size_t)E);
    int2*    part   = (int2*)carve(sizeof(int2) * (size_t)E);
    __bf16*  h      = (__bf16*)carve(sizeof(__bf16) * (size_t)N * 128);
    unsigned char* ybuf = (unsigned char*)carve(sizeof(unsigned char) * (size_t)N * 128);
    float*   yscale = (float*)carve(sizeof(float) * (size_t)N);
    void*    zraw   = carve(sizeof(__bf16) * (size_t)N * 128);  // aliased
    __bf16*  zb     = (__bf16*)zraw;   // LN layers: [N][128] bf16
    float*   zf     = (float*)zraw;    // final layer: [N][64] fp32

    // --- CSR build ---
    (void)hipMemsetAsync(bhist, 0, sizeof(int) * PB_NB, stream);
    const int gridE = (E + PB_CHUNK - 1) / PB_CHUNK;
    coarse_hist<<<gridE, PB_BLOCK, 0, stream>>>(dst, bhist, E);
    coarse_scan<<<1, PB_NB, 0, stream>>>(bhist, bbase, bcur);
    part_scatter<<<gridE, PB_BLOCK, 0, stream>>>(src, dst, bcur, part, E);
    bucket_build<<<PB_NB, 256, 0, stream>>>(part, bbase, offs, ssrc, N, E);

    const int gridM = (N + 63) / 64;
    const int gridNode = (N + 3) / 4;

    // --- Layer 0 (A fp32, converted in staging) ---
    gemm_mfma<128, float, __bf16><<<dim3(gridM, 2), 256, 0, stream>>>(x, Wl0, Wr0, b0, ybuf, yscale, zb, N);
    agg_ln128<<<gridNode, 256, 0, stream>>>(offs, ssrc, ybuf, yscale, zb, g0, be0, h, N);
    // --- Layer 1 ---
    gemm_mfma<128, __bf16, __bf16><<<dim3(gridM, 2), 256, 0, stream>>>(h, Wl1, Wr1, b1, ybuf, yscale, zb, N);
    agg_ln128<<<gridNode, 256, 0, stream>>>(offs, ssrc, ybuf, yscale, zb, g1, be1, h, N);
    // --- Layer 2 (64 feats, z fp32, no LN/ReLU) ---
    gemm_mfma<64, __bf16, float><<<dim3(gridM, 2), 256, 0, stream>>>(h, Wl2, Wr2, b2, ybuf, yscale, zf, N);
    agg_out64<<<gridNode, 256, 0, stream>>>(offs, ssrc, ybuf, yscale, zf, out, N);
}